// Round 1
// 423.833 us; speedup vs baseline: 1.0673x; 1.0673x over previous
//
#include <hip/hip_runtime.h>
#include <cmath>

#define B_   4
#define L_   1024
#define H_   768
#define NH_  12
#define NE_  30
#define M_   6
#define P_   600
#define EMB_ 768
#define BS_  16
#define NC_  97

typedef __bf16 bf16x8 __attribute__((ext_vector_type(8)));
typedef float floatx4 __attribute__((ext_vector_type(4)));

union V16 { uint4 q; __bf16 b[8]; bf16x8 v; };
union V8  { unsigned long long u; __bf16 b[4]; };

// async global->LDS, 16B per lane (dest = wave-uniform base + lane*16)
__device__ __forceinline__ void gload16(const __bf16* g, __bf16* l) {
  __builtin_amdgcn_global_load_lds(
      (const __attribute__((address_space(1))) void*)g,
      (__attribute__((address_space(3))) void*)l, 16, 0, 0);
}

// =================== shared NT MFMA GEMM core ===================
// 64x64 tile, BK=32, 4 waves (2x2 of 32x32), double-buffered LDS staged via
// global_load_lds one K-step ahead; ONE barrier per K-step.
// LDS layout: sm[buf][ A[64][32] | B[64][32] ]  -> 2*4096 elements = 16 KB.
__device__ __forceinline__ void gemm_core(
    const __bf16* __restrict__ A, int lda, long aRow0,
    const __bf16* __restrict__ Bt, int ldb, long bRow0,
    int K, __bf16* sm, floatx4 acc[2][2])
{
  const int tid = threadIdx.x;
  const int lid = tid & 63, w = tid >> 6;
  const int ar = (w & 1) * 32, bc = (w >> 1) * 32;
  const int frow = lid & 15, kg = lid >> 4;
  const int grow = tid >> 2, gq = (tid & 3) * 8;   // row/chunk for staging
  const __bf16* ag = A + (aRow0 + grow) * (long)lda + gq;
  const __bf16* bg = Bt + (bRow0 + grow) * (long)ldb + gq;
  // prologue: stage tile 0 into buf0
  {
    __bf16* wbase = sm + w * 512;
    gload16(ag, wbase);
    gload16(bg, wbase + 2048);
  }
  __syncthreads();   // drains vmcnt -> tile 0 resident
  int cur = 0;
  for (int k0 = 0; k0 < K; k0 += 32) {
    __bf16* As = sm + cur * 4096;
    __bf16* Bs = As + 2048;
    if (k0 + 32 < K) {               // stage NEXT tile while computing this one
      __bf16* An = sm + (cur ^ 1) * 4096 + w * 512;
      gload16(ag + k0 + 32, An);
      gload16(bg + k0 + 32, An + 2048);
    }
    V16 a0, a1, b0, b1;
    a0.q = *reinterpret_cast<const uint4*>(As + (ar + frow) * 32 + kg * 8);
    a1.q = *reinterpret_cast<const uint4*>(As + (ar + 16 + frow) * 32 + kg * 8);
    b0.q = *reinterpret_cast<const uint4*>(Bs + (bc + frow) * 32 + kg * 8);
    b1.q = *reinterpret_cast<const uint4*>(Bs + (bc + 16 + frow) * 32 + kg * 8);
    acc[0][0] = __builtin_amdgcn_mfma_f32_16x16x32_bf16(a0.v, b0.v, acc[0][0], 0, 0, 0);
    acc[0][1] = __builtin_amdgcn_mfma_f32_16x16x32_bf16(a0.v, b1.v, acc[0][1], 0, 0, 0);
    acc[1][0] = __builtin_amdgcn_mfma_f32_16x16x32_bf16(a1.v, b0.v, acc[1][0], 0, 0, 0);
    acc[1][1] = __builtin_amdgcn_mfma_f32_16x16x32_bf16(a1.v, b1.v, acc[1][1], 0, 0, 0);
    __syncthreads();   // next tile staged + everyone done reading cur
    cur ^= 1;
  }
}

// =================== STAGE 1: fused prep ===================
// blocks: [0,2400) cvt weights | [2400,11616) transpose projW |
// [11616,14688) transpose seq | [14688,14808) entity_pool | [14808,16248) entity_att
#define S1_CVT  2400
#define S1_TPW  9216
#define S1_TPS  3072
#define S1_POOL 120
#define S1_ATT  1440

__device__ __forceinline__ void transpose_body(
    const float* __restrict__ in, __bf16* __restrict__ out,
    int R, int C, int bx, int by, float (*t)[33])
{
  int c0 = bx*32, r0 = by*32;
  int tx = threadIdx.x & 31, ty = threadIdx.x >> 5;
#pragma unroll
  for (int p = 0; p < 4; ++p)
    t[ty + p*8][tx] = in[(long)(r0 + ty + p*8)*C + c0 + tx];
  __syncthreads();
#pragma unroll
  for (int p = 0; p < 4; ++p)
    out[(long)(c0 + ty + p*8)*R + r0 + tx] = (__bf16)t[tx][ty + p*8];
}

__global__ __launch_bounds__(256) void k_prep(
    const float* __restrict__ seq, const float* __restrict__ att,
    const float* __restrict__ headW, const float* __restrict__ tailW,
    const float* __restrict__ projW, const float* __restrict__ clsW,
    const float* __restrict__ mmask, const int* __restrict__ midx,
    __bf16* __restrict__ Wt, __bf16* __restrict__ clsA,
    __bf16* __restrict__ projWT, __bf16* __restrict__ seqT,
    __bf16* __restrict__ e_embB, __bf16* __restrict__ e_att)
{
  __shared__ float t[32][33];
  int blk = blockIdx.x;
  int tid = threadIdx.x;
  if (blk < S1_CVT) {
    int gid = blk*256 + tid;
    if (gid < 2*H_*384) {
      int sel = gid / (H_*384);
      int rem = gid % (H_*384);
      int o = rem / 384;
      int k4 = (rem % 384) * 4;
      const float* W = sel ? tailW : headW;
      float4 v = *reinterpret_cast<const float4*>(W + (long)o*(2*H_) + k4);
      V8 d; d.b[0]=(__bf16)v.x; d.b[1]=(__bf16)v.y; d.b[2]=(__bf16)v.z; d.b[3]=(__bf16)v.w;
      *reinterpret_cast<unsigned long long*>(Wt + ((long)sel*H_ + o)*(2*H_) + k4) = d.u;
    } else {
      int rem = gid - 2*H_*384;
      int row = rem / 192;
      int k4 = (rem % 192) * 4;
      V8 d;
      if (row < NC_) {
        float4 v = *reinterpret_cast<const float4*>(clsW + (long)row*H_ + k4);
        d.b[0]=(__bf16)v.x; d.b[1]=(__bf16)v.y; d.b[2]=(__bf16)v.z; d.b[3]=(__bf16)v.w;
      } else {
        d.b[0]=d.b[1]=d.b[2]=d.b[3]=(__bf16)0.f;
      }
      *reinterpret_cast<unsigned long long*>(clsA + (long)row*H_ + k4) = d.u;
    }
  } else if (blk < S1_CVT + S1_TPW) {
    int b = blk - S1_CVT;
    transpose_body(projW, projWT, H_, EMB_*BS_, b % 384, b / 384, t);
  } else if (blk < S1_CVT + S1_TPW + S1_TPS) {
    int b = blk - (S1_CVT + S1_TPW);
    int bx = b % 24, by = (b / 24) % 32, bz = b / (24*32);
    transpose_body(seq + (long)bz*L_*H_, seqT + (long)bz*H_*L_, L_, H_, bx, by, t);
  } else if (blk < S1_CVT + S1_TPW + S1_TPS + S1_POOL) {
    int be = blk - (S1_CVT + S1_TPW + S1_TPS);
    int idx[M_]; float msk[M_];
#pragma unroll
    for (int m = 0; m < M_; ++m) {
      idx[m] = midx[be * M_ + m];
      msk[m] = mmask[be * M_ + m];
    }
    int b = be / NE_;
    const float* sb = seq + (size_t)b * L_ * H_;
    for (int h = tid; h < H_; h += 256) {
      float v[M_]; float mx = -3.0e38f;
#pragma unroll
      for (int m = 0; m < M_; ++m) {
        float x = (msk[m] > 0.f) ? sb[(size_t)idx[m] * H_ + h] : -1e30f;
        v[m] = x; mx = fmaxf(mx, x);
      }
      float s = 0.f;
#pragma unroll
      for (int m = 0; m < M_; ++m) s += expf(v[m] - mx);
      e_embB[(size_t)be * H_ + h] = (__bf16)(mx + logf(s));
    }
  } else {
    int i = (blk - (S1_CVT + S1_TPW + S1_TPS + S1_POOL))*256 + tid;
    int l4 = (i & 255) * 4;
    int nh = (i >> 8) % NH_;
    int be = i / (256 * NH_);
    int b  = be / NE_;
    float s0=0.f, s1=0.f, s2=0.f, s3=0.f, cnt=0.f;
#pragma unroll
    for (int m = 0; m < M_; ++m) {
      float mk = mmask[be*M_ + m];
      cnt += mk;
      int id = midx[be*M_ + m];
      float4 a = *reinterpret_cast<const float4*>(
          att + (((size_t)b*NH_ + nh)*L_ + id)*L_ + l4);
      s0 += mk*a.x; s1 += mk*a.y; s2 += mk*a.z; s3 += mk*a.w;
    }
    float inv = 1.f / fmaxf(cnt, 1.f);
    V8 o;
    o.b[0]=(__bf16)(s0*inv); o.b[1]=(__bf16)(s1*inv);
    o.b[2]=(__bf16)(s2*inv); o.b[3]=(__bf16)(s3*inv);
    *reinterpret_cast<unsigned long long*>(e_att + ((size_t)be*NH_ + nh)*L_ + l4) = o.u;
  }
}

// =================== STAGE 2: fused wc + pre + htatt ===================
// blocks: [0,384) wc | [384,432) pre (heavy GEMMs first) | [432,2832) htatt
#define S2_WC  384
#define S2_PRE 48
#define S2_HT  2400

__global__ __launch_bounds__(256) void k_mid(
    const __bf16* __restrict__ clsA, const __bf16* __restrict__ projWT,
    const __bf16* __restrict__ e_att, const int* __restrict__ hts,
    const __bf16* __restrict__ e_embB, const __bf16* __restrict__ Wt,
    __bf16* __restrict__ WcT, __bf16* __restrict__ htatt,
    float* __restrict__ hpre, float* __restrict__ tpre)
{
  __shared__ __bf16 sm[2*4096];   // 16 KB: double-buffered A|B tiles
  int blk = blockIdx.x;
  int tid = threadIdx.x;
  if (blk < S2_WC) {
    int n0 = (blk % 192)*64, r0 = (blk / 192)*64;
    floatx4 acc[2][2] = {};
    gemm_core(clsA, H_, r0, projWT, H_, n0, H_, sm, acc);
    int lid = tid & 63, w = tid >> 6;
    int ar = (w&1)*32, bc = (w>>1)*32, frow = lid&15, kg = lid>>4;
#pragma unroll
    for (int i = 0; i < 2; ++i)
#pragma unroll
      for (int r = 0; r < 4; ++r) {
        int c = r0 + ar + i*16 + kg*4 + r;
#pragma unroll
        for (int j = 0; j < 2; ++j)
          WcT[(long)c*(EMB_*BS_) + n0 + bc + j*16 + frow] = (__bf16)acc[i][j][r];
      }
  } else if (blk < S2_WC + S2_PRE) {
    int tb = blk - S2_WC;
    int o0 = (tb % 12)*64;
    int r0 = ((tb / 12) & 1)*64;
    int sel = tb / 24;
    floatx4 acc[2][2] = {};
    gemm_core(e_embB, H_, r0, Wt + (long)sel*H_*(2*H_), 2*H_, o0, H_, sm, acc);
    float* out = sel ? tpre : hpre;
    int lid = tid & 63, w = tid >> 6;
    int ar = (w&1)*32, bc = (w>>1)*32, frow = lid&15, kg = lid>>4;
#pragma unroll
    for (int i = 0; i < 2; ++i)
#pragma unroll
      for (int r = 0; r < 4; ++r) {
        int be = r0 + ar + i*16 + kg*4 + r;
        if (be < B_*NE_) {
#pragma unroll
          for (int j = 0; j < 2; ++j)
            out[(long)be*EMB_ + o0 + bc + j*16 + frow] = acc[i][j][r];
        }
      }
  } else {
    int bp = blk - (S2_WC + S2_PRE);
    int b = bp / P_;
    int hi = hts[bp*2 + 0], ti = hts[bp*2 + 1];
    const __bf16* ha = e_att + (size_t)(b*NE_ + hi) * NH_ * L_;
    const __bf16* ta = e_att + (size_t)(b*NE_ + ti) * NH_ * L_;
    int l4 = tid * 4;
    float v[4] = {0.f,0.f,0.f,0.f};
#pragma unroll
    for (int nh = 0; nh < NH_; ++nh) {
      V8 x, y;
      x.u = *reinterpret_cast<const unsigned long long*>(ha + nh*L_ + l4);
      y.u = *reinterpret_cast<const unsigned long long*>(ta + nh*L_ + l4);
#pragma unroll
      for (int q = 0; q < 4; ++q) v[q] += (float)x.b[q] * (float)y.b[q];
    }
    float loc = 0.f;
#pragma unroll
    for (int q = 0; q < 4; ++q) { v[q] *= (1.f/NH_); loc += v[q]; }
    float* red = reinterpret_cast<float*>(sm);
    for (int off = 32; off > 0; off >>= 1) loc += __shfl_down(loc, off, 64);
    if ((tid & 63) == 0) red[tid >> 6] = loc;
    __syncthreads();
    float inv = 1.f / (red[0] + red[1] + red[2] + red[3] + 1e-30f);
    V8 o;
#pragma unroll
    for (int q = 0; q < 4; ++q) o.b[q] = (__bf16)(v[q] * inv);
    *reinterpret_cast<unsigned long long*>(htatt + (size_t)bp*L_ + l4) = o.u;
  }
}

// =================== STAGE 3: rs ===================
__global__ __launch_bounds__(256) void k_rs_mfma(
    const __bf16* __restrict__ htatt, const __bf16* __restrict__ seqT,
    __bf16* __restrict__ rs)
{
  __shared__ __bf16 sm[2*4096];
  int b = blockIdx.z, p0 = blockIdx.y*64, h0 = blockIdx.x*64;
  floatx4 acc[2][2] = {};
  gemm_core(htatt, L_, (long)b*P_ + p0, seqT + (long)b*H_*L_, L_, h0, L_, sm, acc);
  int lid = threadIdx.x & 63, w = threadIdx.x >> 6;
  int ar = (w&1)*32, bc = (w>>1)*32, frow = lid&15, kg = lid>>4;
#pragma unroll
  for (int i = 0; i < 2; ++i)
#pragma unroll
    for (int r = 0; r < 4; ++r) {
      int p = p0 + ar + i*16 + kg*4 + r;
      if (p < P_) {
#pragma unroll
        for (int j = 0; j < 2; ++j)
          rs[((long)b*P_ + p)*H_ + h0 + bc + j*16 + frow] = (__bf16)acc[i][j][r];
      }
    }
}

// =================== STAGE 4: extract ===================
__global__ __launch_bounds__(256) void k_extract_mfma(
    const __bf16* __restrict__ rs, const __bf16* __restrict__ Wt,
    const float* __restrict__ headb, const float* __restrict__ tailb,
    const float* __restrict__ hpre, const float* __restrict__ tpre,
    const int* __restrict__ hts, __bf16* __restrict__ hs, __bf16* __restrict__ ts)
{
  __shared__ __bf16 sm[2*4096];
  int sel = blockIdx.z, r0 = blockIdx.y*64, o0 = blockIdx.x*64;
  const float* bias = sel ? tailb : headb;
  const float* pre = sel ? tpre : hpre;
  __bf16* out = sel ? ts : hs;
  floatx4 acc[2][2] = {};
  gemm_core(rs, H_, r0, Wt + (long)sel*H_*(2*H_) + H_, 2*H_, o0, H_, sm, acc);
  int lid = threadIdx.x & 63, w = threadIdx.x >> 6;
  int ar = (w&1)*32, bc = (w>>1)*32, frow = lid&15, kg = lid>>4;
#pragma unroll
  for (int i = 0; i < 2; ++i)
#pragma unroll
    for (int r = 0; r < 4; ++r) {
      int row = r0 + ar + i*16 + kg*4 + r;
      if (row < B_*P_) {
        int b = row / P_;
        int e = hts[row*2 + sel];
        const float* prow = pre + (long)(b*NE_ + e) * EMB_;
#pragma unroll
        for (int j = 0; j < 2; ++j) {
          int o = o0 + bc + j*16 + frow;
          out[(long)row*EMB_ + o] = (__bf16)tanhf(acc[i][j][r] + prow[o] + bias[o]);
        }
      }
    }
}

// =================== STAGE 5: logits (K-split x4, atomic combine) ===================
__global__ __launch_bounds__(512) void k_logits_mfma(
    const __bf16* __restrict__ hs, const __bf16* __restrict__ ts,
    const __bf16* __restrict__ WcT, const float* __restrict__ clsb,
    float* __restrict__ out)
{
  int r0 = (blockIdx.x >> 2) * 16;     // 150 row-tiles
  int ks = blockIdx.x & 3;             // 4-way K split
  int tid = threadIdx.x;
  int w = tid >> 6, lid = tid & 63;
  int frow = lid & 15, kg = lid >> 4;
  int row = r0 + frow;
  long hsrow = (long)row * EMB_;
  floatx4 acc[7] = {};
  int kbase0 = ks*3072 + w*384;
  for (int s = 0; s < 12; ++s) {
    int kb = kbase0 + s*32 + kg*8;
    int q16 = (kb >> 8) << 4;
    int ii = (kb >> 4) & 15;
    int jj0 = kb & 15;
    float hv = (float)hs[hsrow + q16 + ii];
    V16 tsv; tsv.q = *reinterpret_cast<const uint4*>(ts + hsrow + q16 + jj0);
    bf16x8 af;
#pragma unroll
    for (int j = 0; j < 8; ++j) af[j] = (__bf16)(hv * (float)tsv.b[j]);
#pragma unroll
    for (int f = 0; f < 7; ++f) {
      V16 bv; bv.q = *reinterpret_cast<const uint4*>(WcT + (long)(f*16 + frow)*(EMB_*BS_) + kb);
      acc[f] = __builtin_amdgcn_mfma_f32_16x16x32_bf16(af, bv.v, acc[f], 0, 0, 0);
    }
  }
  __shared__ float red[8][16][112];
#pragma unroll
  for (int f = 0; f < 7; ++f)
#pragma unroll
    for (int r = 0; r < 4; ++r)
      red[w][kg*4 + r][f*16 + frow] = acc[f][r];
  __syncthreads();
  for (int e = tid; e < 16*112; e += 512) {
    int rr = e / 112, cc = e % 112;
    if (cc < NC_) {
      float s = (ks == 0) ? clsb[cc] : 0.f;
#pragma unroll
      for (int ww = 0; ww < 8; ++ww) s += red[ww][rr][cc];
      atomicAdd(out + (long)(r0 + rr)*NC_ + cc, s);
    }
  }
}

extern "C" void kernel_launch(void* const* d_in, const int* in_sizes, int n_in,
                              void* d_out, int out_size, void* d_ws, size_t ws_size,
                              hipStream_t stream) {
  const float* seq   = (const float*)d_in[0];
  const float* att   = (const float*)d_in[1];
  const float* headW = (const float*)d_in[2];
  const float* headb = (const float*)d_in[3];
  const float* tailW = (const float*)d_in[4];
  const float* tailb = (const float*)d_in[5];
  const float* projW = (const float*)d_in[6];
  const float* clsW  = (const float*)d_in[7];
  const float* clsb  = (const float*)d_in[8];
  const float* mmask = (const float*)d_in[9];
  const int* midx = (const int*)d_in[10];
  const int* hts  = (const int*)d_in[11];

  char* p = (char*)d_ws;
  auto alloc_f = [&](size_t n){ float* r = (float*)p; p += n*sizeof(float); return r; };
  auto alloc_b = [&](size_t n){ __bf16* r = (__bf16*)p; p += n*2; return r; };
  float* hpre    = alloc_f((size_t)B_*NE_*EMB_);
  float* tpre    = alloc_f((size_t)B_*NE_*EMB_);
  __bf16* e_embB = alloc_b((size_t)128*H_);
  __bf16* e_att  = alloc_b((size_t)B_*NE_*NH_*L_);
  __bf16* htattb = alloc_b((size_t)2464*L_);
  __bf16* seqT   = alloc_b((size_t)B_*H_*L_);
  __bf16* rsb    = alloc_b((size_t)2432*H_);
  __bf16* Wt     = alloc_b((size_t)2*H_*2*H_);
  __bf16* clsA   = alloc_b((size_t)128*H_);
  __bf16* WcT    = alloc_b((size_t)128*EMB_*BS_);
  __bf16* projWT = alloc_b((size_t)EMB_*BS_*H_);
  // hs/ts alias projWT (projWT dead after k_mid's wc branch)
  __bf16* hsb = projWT;
  __bf16* tsb = projWT + (size_t)B_*P_*EMB_;

  // zero output for the K-split atomic combine in k_logits
  hipMemsetAsync(d_out, 0, (size_t)B_*P_*NC_*sizeof(float), stream);

  k_prep<<<S1_CVT + S1_TPW + S1_TPS + S1_POOL + S1_ATT, 256, 0, stream>>>(
      seq, att, headW, tailW, projW, clsW, mmask, midx,
      Wt, clsA, projWT, seqT, e_embB, e_att);
  k_mid<<<S2_WC + S2_PRE + S2_HT, 256, 0, stream>>>(
      clsA, projWT, e_att, hts, e_embB, Wt, WcT, htattb, hpre, tpre);
  k_rs_mfma<<<dim3(H_/64, 10, B_), 256, 0, stream>>>(htattb, seqT, rsb);
  k_extract_mfma<<<dim3(EMB_/64, 38, 2), 256, 0, stream>>>(
      rsb, Wt, headb, tailb, hpre, tpre, hts, hsb, tsb);
  k_logits_mfma<<<600, 512, 0, stream>>>(hsb, tsb, WcT, clsb, (float*)d_out);
}

// Round 3
// 420.403 us; speedup vs baseline: 1.0760x; 1.0082x over previous
//
#include <hip/hip_runtime.h>
#include <cmath>

#define B_   4
#define L_   1024
#define H_   768
#define NH_  12
#define NE_  30
#define M_   6
#define P_   600
#define EMB_ 768
#define BS_  16
#define NC_  97

typedef __bf16 bf16x8 __attribute__((ext_vector_type(8)));
typedef float floatx4 __attribute__((ext_vector_type(4)));

union V16 { uint4 q; __bf16 b[8]; bf16x8 v; };
union V8  { unsigned long long u; __bf16 b[4]; };

// async global->LDS, 16B per lane (dest = wave-uniform base + lane*16)
__device__ __forceinline__ void gload16(const __bf16* g, __bf16* l) {
  __builtin_amdgcn_global_load_lds(
      (const __attribute__((address_space(1))) void*)g,
      (__attribute__((address_space(3))) void*)l, 16, 0, 0);
}

// =================== shared NT MFMA GEMM core ===================
// 64x64 tile, BK=32, 4 waves (2x2 of 32x32).
// 3 LDS buffers, prefetch distance 2, counted s_waitcnt vmcnt(2) -- loads stay
// in flight ACROSS barriers (T4); vmcnt(0) only on the final tile.
// LDS: sm[3][ A[64][32] | B[64][32] ] = 3*4096 elems = 24 KB.
__device__ __forceinline__ void mfma_step(
    const __bf16* As, const __bf16* Bs,
    int ar, int bc, int frow, int kg, floatx4 acc[2][2])
{
  V16 a0, a1, b0, b1;
  a0.q = *reinterpret_cast<const uint4*>(As + (ar + frow) * 32 + kg * 8);
  a1.q = *reinterpret_cast<const uint4*>(As + (ar + 16 + frow) * 32 + kg * 8);
  b0.q = *reinterpret_cast<const uint4*>(Bs + (bc + frow) * 32 + kg * 8);
  b1.q = *reinterpret_cast<const uint4*>(Bs + (bc + 16 + frow) * 32 + kg * 8);
  acc[0][0] = __builtin_amdgcn_mfma_f32_16x16x32_bf16(a0.v, b0.v, acc[0][0], 0, 0, 0);
  acc[0][1] = __builtin_amdgcn_mfma_f32_16x16x32_bf16(a0.v, b1.v, acc[0][1], 0, 0, 0);
  acc[1][0] = __builtin_amdgcn_mfma_f32_16x16x32_bf16(a1.v, b0.v, acc[1][0], 0, 0, 0);
  acc[1][1] = __builtin_amdgcn_mfma_f32_16x16x32_bf16(a1.v, b1.v, acc[1][1], 0, 0, 0);
}

__device__ __forceinline__ void gemm_core(
    const __bf16* __restrict__ A, int lda, long aRow0,
    const __bf16* __restrict__ Bt, int ldb, long bRow0,
    int K, __bf16* sm, floatx4 acc[2][2])
{
  const int tid = threadIdx.x;
  const int lid = tid & 63, w = tid >> 6;
  const int ar = (w & 1) * 32, bc = (w >> 1) * 32;
  const int frow = lid & 15, kg = lid >> 4;
  const int grow = tid >> 2, gq = (tid & 3) * 8;   // row/chunk for staging
  const __bf16* ag = A + (aRow0 + grow) * (long)lda + gq;
  const __bf16* bg = Bt + (bRow0 + grow) * (long)ldb + gq;
  __bf16* wA = sm + w * 512;          // this wave's staging slice within a buffer
  const int nt = K >> 5;
  // prologue: stage tiles 0 and 1 into buffers 0 and 1
  gload16(ag, wA);
  gload16(bg, wA + 2048);
  gload16(ag + 32, wA + 4096);
  gload16(bg + 32, wA + 4096 + 2048);
  int cur = 0;
  for (int i = 0; i < nt - 1; ++i) {
    asm volatile("s_waitcnt vmcnt(2)" ::: "memory");   // tile i resident (this wave)
    __builtin_amdgcn_s_barrier();                      // -> resident for all waves
    __builtin_amdgcn_sched_barrier(0);
    if (i + 2 < nt) {                  // issue tile i+2 while computing tile i
      int nb = cur + 2; if (nb >= 3) nb -= 3;
      __bf16* d = sm + nb * 4096 + w * 512;
      gload16(ag + (i + 2) * 32, d);
      gload16(bg + (i + 2) * 32, d + 2048);
    }
    const __bf16* As = sm + cur * 4096;
    mfma_step(As, As + 2048, ar, bc, frow, kg, acc);
    cur += 1; if (cur == 3) cur = 0;
  }
  asm volatile("s_waitcnt vmcnt(0)" ::: "memory");     // final tile
  __builtin_amdgcn_s_barrier();
  __builtin_amdgcn_sched_barrier(0);
  const __bf16* As = sm + cur * 4096;
  mfma_step(As, As + 2048, ar, bc, frow, kg, acc);
}

// =================== STAGE 1: fused prep ===================
// blocks: [0,2400) cvt weights | [2400,11616) transpose projW |
// [11616,14688) transpose seq | [14688,14808) entity_pool | [14808,16248) entity_att
#define S1_CVT  2400
#define S1_TPW  9216
#define S1_TPS  3072
#define S1_POOL 120
#define S1_ATT  1440

__device__ __forceinline__ void transpose_body(
    const float* __restrict__ in, __bf16* __restrict__ out,
    int R, int C, int bx, int by, float (*t)[33])
{
  int c0 = bx*32, r0 = by*32;
  int tx = threadIdx.x & 31, ty = threadIdx.x >> 5;
#pragma unroll
  for (int p = 0; p < 4; ++p)
    t[ty + p*8][tx] = in[(long)(r0 + ty + p*8)*C + c0 + tx];
  __syncthreads();
#pragma unroll
  for (int p = 0; p < 4; ++p)
    out[(long)(c0 + ty + p*8)*R + r0 + tx] = (__bf16)t[tx][ty + p*8];
}

__global__ __launch_bounds__(256) void k_prep(
    const float* __restrict__ seq, const float* __restrict__ att,
    const float* __restrict__ headW, const float* __restrict__ tailW,
    const float* __restrict__ projW, const float* __restrict__ clsW,
    const float* __restrict__ mmask, const int* __restrict__ midx,
    __bf16* __restrict__ Wt, __bf16* __restrict__ clsA,
    __bf16* __restrict__ projWT, __bf16* __restrict__ seqT,
    __bf16* __restrict__ e_embB, __bf16* __restrict__ e_att)
{
  __shared__ float t[32][33];
  int blk = blockIdx.x;
  int tid = threadIdx.x;
  if (blk < S1_CVT) {
    int gid = blk*256 + tid;
    if (gid < 2*H_*384) {
      int sel = gid / (H_*384);
      int rem = gid % (H_*384);
      int o = rem / 384;
      int k4 = (rem % 384) * 4;
      const float* W = sel ? tailW : headW;
      float4 v = *reinterpret_cast<const float4*>(W + (long)o*(2*H_) + k4);
      V8 d; d.b[0]=(__bf16)v.x; d.b[1]=(__bf16)v.y; d.b[2]=(__bf16)v.z; d.b[3]=(__bf16)v.w;
      *reinterpret_cast<unsigned long long*>(Wt + ((long)sel*H_ + o)*(2*H_) + k4) = d.u;
    } else {
      int rem = gid - 2*H_*384;
      int row = rem / 192;
      int k4 = (rem % 192) * 4;
      V8 d;
      if (row < NC_) {
        float4 v = *reinterpret_cast<const float4*>(clsW + (long)row*H_ + k4);
        d.b[0]=(__bf16)v.x; d.b[1]=(__bf16)v.y; d.b[2]=(__bf16)v.z; d.b[3]=(__bf16)v.w;
      } else {
        d.b[0]=d.b[1]=d.b[2]=d.b[3]=(__bf16)0.f;
      }
      *reinterpret_cast<unsigned long long*>(clsA + (long)row*H_ + k4) = d.u;
    }
  } else if (blk < S1_CVT + S1_TPW) {
    int b = blk - S1_CVT;
    transpose_body(projW, projWT, H_, EMB_*BS_, b % 384, b / 384, t);
  } else if (blk < S1_CVT + S1_TPW + S1_TPS) {
    int b = blk - (S1_CVT + S1_TPW);
    int bx = b % 24, by = (b / 24) % 32, bz = b / (24*32);
    transpose_body(seq + (long)bz*L_*H_, seqT + (long)bz*H_*L_, L_, H_, bx, by, t);
  } else if (blk < S1_CVT + S1_TPW + S1_TPS + S1_POOL) {
    int be = blk - (S1_CVT + S1_TPW + S1_TPS);
    int idx[M_]; float msk[M_];
#pragma unroll
    for (int m = 0; m < M_; ++m) {
      idx[m] = midx[be * M_ + m];
      msk[m] = mmask[be * M_ + m];
    }
    int b = be / NE_;
    const float* sb = seq + (size_t)b * L_ * H_;
    for (int h = tid; h < H_; h += 256) {
      float v[M_]; float mx = -3.0e38f;
#pragma unroll
      for (int m = 0; m < M_; ++m) {
        float x = (msk[m] > 0.f) ? sb[(size_t)idx[m] * H_ + h] : -1e30f;
        v[m] = x; mx = fmaxf(mx, x);
      }
      float s = 0.f;
#pragma unroll
      for (int m = 0; m < M_; ++m) s += expf(v[m] - mx);
      e_embB[(size_t)be * H_ + h] = (__bf16)(mx + logf(s));
    }
  } else {
    int i = (blk - (S1_CVT + S1_TPW + S1_TPS + S1_POOL))*256 + tid;
    int l4 = (i & 255) * 4;
    int nh = (i >> 8) % NH_;
    int be = i / (256 * NH_);
    int b  = be / NE_;
    float s0=0.f, s1=0.f, s2=0.f, s3=0.f, cnt=0.f;
#pragma unroll
    for (int m = 0; m < M_; ++m) {
      float mk = mmask[be*M_ + m];
      cnt += mk;
      int id = midx[be*M_ + m];
      float4 a = *reinterpret_cast<const float4*>(
          att + (((size_t)b*NH_ + nh)*L_ + id)*L_ + l4);
      s0 += mk*a.x; s1 += mk*a.y; s2 += mk*a.z; s3 += mk*a.w;
    }
    float inv = 1.f / fmaxf(cnt, 1.f);
    V8 o;
    o.b[0]=(__bf16)(s0*inv); o.b[1]=(__bf16)(s1*inv);
    o.b[2]=(__bf16)(s2*inv); o.b[3]=(__bf16)(s3*inv);
    *reinterpret_cast<unsigned long long*>(e_att + ((size_t)be*NH_ + nh)*L_ + l4) = o.u;
  }
}

// =================== STAGE 2: fused wc + pre + htatt ===================
// blocks: [0,384) wc | [384,432) pre (heavy GEMMs first) | [432,2832) htatt
#define S2_WC  384
#define S2_PRE 48
#define S2_HT  2400

__global__ __launch_bounds__(256) void k_mid(
    const __bf16* __restrict__ clsA, const __bf16* __restrict__ projWT,
    const __bf16* __restrict__ e_att, const int* __restrict__ hts,
    const __bf16* __restrict__ e_embB, const __bf16* __restrict__ Wt,
    __bf16* __restrict__ WcT, __bf16* __restrict__ htatt,
    float* __restrict__ hpre, float* __restrict__ tpre)
{
  __shared__ __bf16 sm[3*4096];   // 24 KB: triple-buffered A|B tiles
  int blk = blockIdx.x;
  int tid = threadIdx.x;
  if (blk < S2_WC) {
    int n0 = (blk % 192)*64, r0 = (blk / 192)*64;
    floatx4 acc[2][2] = {};
    gemm_core(clsA, H_, r0, projWT, H_, n0, H_, sm, acc);
    int lid = tid & 63, w = tid >> 6;
    int ar = (w&1)*32, bc = (w>>1)*32, frow = lid&15, kg = lid>>4;
#pragma unroll
    for (int i = 0; i < 2; ++i)
#pragma unroll
      for (int r = 0; r < 4; ++r) {
        int c = r0 + ar + i*16 + kg*4 + r;
#pragma unroll
        for (int j = 0; j < 2; ++j)
          WcT[(long)c*(EMB_*BS_) + n0 + bc + j*16 + frow] = (__bf16)acc[i][j][r];
      }
  } else if (blk < S2_WC + S2_PRE) {
    int tb = blk - S2_WC;
    int o0 = (tb % 12)*64;
    int r0 = ((tb / 12) & 1)*64;
    int sel = tb / 24;
    floatx4 acc[2][2] = {};
    gemm_core(e_embB, H_, r0, Wt + (long)sel*H_*(2*H_), 2*H_, o0, H_, sm, acc);
    float* out = sel ? tpre : hpre;
    int lid = tid & 63, w = tid >> 6;
    int ar = (w&1)*32, bc = (w>>1)*32, frow = lid&15, kg = lid>>4;
#pragma unroll
    for (int i = 0; i < 2; ++i)
#pragma unroll
      for (int r = 0; r < 4; ++r) {
        int be = r0 + ar + i*16 + kg*4 + r;
        if (be < B_*NE_) {
#pragma unroll
          for (int j = 0; j < 2; ++j)
            out[(long)be*EMB_ + o0 + bc + j*16 + frow] = acc[i][j][r];
        }
      }
  } else {
    int bp = blk - (S2_WC + S2_PRE);
    int b = bp / P_;
    int hi = hts[bp*2 + 0], ti = hts[bp*2 + 1];
    const __bf16* ha = e_att + (size_t)(b*NE_ + hi) * NH_ * L_;
    const __bf16* ta = e_att + (size_t)(b*NE_ + ti) * NH_ * L_;
    int l4 = tid * 4;
    float v[4] = {0.f,0.f,0.f,0.f};
#pragma unroll
    for (int nh = 0; nh < NH_; ++nh) {
      V8 x, y;
      x.u = *reinterpret_cast<const unsigned long long*>(ha + nh*L_ + l4);
      y.u = *reinterpret_cast<const unsigned long long*>(ta + nh*L_ + l4);
#pragma unroll
      for (int q = 0; q < 4; ++q) v[q] += (float)x.b[q] * (float)y.b[q];
    }
    float loc = 0.f;
#pragma unroll
    for (int q = 0; q < 4; ++q) { v[q] *= (1.f/NH_); loc += v[q]; }
    float* red = reinterpret_cast<float*>(sm);
    for (int off = 32; off > 0; off >>= 1) loc += __shfl_down(loc, off, 64);
    if ((tid & 63) == 0) red[tid >> 6] = loc;
    __syncthreads();
    float inv = 1.f / (red[0] + red[1] + red[2] + red[3] + 1e-30f);
    V8 o;
#pragma unroll
    for (int q = 0; q < 4; ++q) o.b[q] = (__bf16)(v[q] * inv);
    *reinterpret_cast<unsigned long long*>(htatt + (size_t)bp*L_ + l4) = o.u;
  }
}

// =================== STAGE 3: rs ===================
__global__ __launch_bounds__(256) void k_rs_mfma(
    const __bf16* __restrict__ htatt, const __bf16* __restrict__ seqT,
    __bf16* __restrict__ rs)
{
  __shared__ __bf16 sm[3*4096];
  int b = blockIdx.z, p0 = blockIdx.y*64, h0 = blockIdx.x*64;
  floatx4 acc[2][2] = {};
  gemm_core(htatt, L_, (long)b*P_ + p0, seqT + (long)b*H_*L_, L_, h0, L_, sm, acc);
  int lid = threadIdx.x & 63, w = threadIdx.x >> 6;
  int ar = (w&1)*32, bc = (w>>1)*32, frow = lid&15, kg = lid>>4;
#pragma unroll
  for (int i = 0; i < 2; ++i)
#pragma unroll
    for (int r = 0; r < 4; ++r) {
      int p = p0 + ar + i*16 + kg*4 + r;
      if (p < P_) {
#pragma unroll
        for (int j = 0; j < 2; ++j)
          rs[((long)b*P_ + p)*H_ + h0 + bc + j*16 + frow] = (__bf16)acc[i][j][r];
      }
    }
}

// =================== STAGE 4: extract ===================
__global__ __launch_bounds__(256) void k_extract_mfma(
    const __bf16* __restrict__ rs, const __bf16* __restrict__ Wt,
    const float* __restrict__ headb, const float* __restrict__ tailb,
    const float* __restrict__ hpre, const float* __restrict__ tpre,
    const int* __restrict__ hts, __bf16* __restrict__ hs, __bf16* __restrict__ ts)
{
  __shared__ __bf16 sm[3*4096];
  int sel = blockIdx.z, r0 = blockIdx.y*64, o0 = blockIdx.x*64;
  const float* bias = sel ? tailb : headb;
  const float* pre = sel ? tpre : hpre;
  __bf16* out = sel ? ts : hs;
  floatx4 acc[2][2] = {};
  gemm_core(rs, H_, r0, Wt + (long)sel*H_*(2*H_) + H_, 2*H_, o0, H_, sm, acc);
  int lid = threadIdx.x & 63, w = threadIdx.x >> 6;
  int ar = (w&1)*32, bc = (w>>1)*32, frow = lid&15, kg = lid>>4;
#pragma unroll
  for (int i = 0; i < 2; ++i)
#pragma unroll
    for (int r = 0; r < 4; ++r) {
      int row = r0 + ar + i*16 + kg*4 + r;
      if (row < B_*P_) {
        int b = row / P_;
        int e = hts[row*2 + sel];
        const float* prow = pre + (long)(b*NE_ + e) * EMB_;
#pragma unroll
        for (int j = 0; j < 2; ++j) {
          int o = o0 + bc + j*16 + frow;
          out[(long)row*EMB_ + o] = (__bf16)tanhf(acc[i][j][r] + prow[o] + bias[o]);
        }
      }
    }
}

// =================== STAGE 5: logits (K-split x4, atomic combine) ===================
__global__ __launch_bounds__(512) void k_logits_mfma(
    const __bf16* __restrict__ hs, const __bf16* __restrict__ ts,
    const __bf16* __restrict__ WcT, const float* __restrict__ clsb,
    float* __restrict__ out)
{
  int r0 = (blockIdx.x >> 2) * 16;     // 150 row-tiles
  int ks = blockIdx.x & 3;             // 4-way K split
  int tid = threadIdx.x;
  int w = tid >> 6, lid = tid & 63;
  int frow = lid & 15, kg = lid >> 4;
  int row = r0 + frow;
  long hsrow = (long)row * EMB_;
  floatx4 acc[7] = {};
  int kbase0 = ks*3072 + w*384;
  for (int s = 0; s < 12; ++s) {
    int kb = kbase0 + s*32 + kg*8;
    int q16 = (kb >> 8) << 4;
    int ii = (kb >> 4) & 15;
    int jj0 = kb & 15;
    float hv = (float)hs[hsrow + q16 + ii];
    V16 tsv; tsv.q = *reinterpret_cast<const uint4*>(ts + hsrow + q16 + jj0);
    bf16x8 af;
#pragma unroll
    for (int j = 0; j < 8; ++j) af[j] = (__bf16)(hv * (float)tsv.b[j]);
#pragma unroll
    for (int f = 0; f < 7; ++f) {
      V16 bv; bv.q = *reinterpret_cast<const uint4*>(WcT + (long)(f*16 + frow)*(EMB_*BS_) + kb);
      acc[f] = __builtin_amdgcn_mfma_f32_16x16x32_bf16(af, bv.v, acc[f], 0, 0, 0);
    }
  }
  // two-phase cross-wave reduction: 28 KB LDS -> 5 blocks/CU (was 57 KB -> 2)
  __shared__ float red[4][16][112];
#pragma unroll
  for (int f = 0; f < 7; ++f)
#pragma unroll
    for (int r = 0; r < 4; ++r) {
      if (w < 4) red[w][kg*4 + r][f*16 + frow] = acc[f][r];
    }
  __syncthreads();
#pragma unroll
  for (int f = 0; f < 7; ++f)
#pragma unroll
    for (int r = 0; r < 4; ++r) {
      if (w >= 4) red[w-4][kg*4 + r][f*16 + frow] += acc[f][r];
    }
  __syncthreads();
  for (int e = tid; e < 16*112; e += 512) {
    int rr = e / 112, cc = e % 112;
    if (cc < NC_) {
      float s = (ks == 0) ? clsb[cc] : 0.f;
#pragma unroll
      for (int ww = 0; ww < 4; ++ww) s += red[ww][rr][cc];
      atomicAdd(out + (long)(r0 + rr)*NC_ + cc, s);
    }
  }
}

extern "C" void kernel_launch(void* const* d_in, const int* in_sizes, int n_in,
                              void* d_out, int out_size, void* d_ws, size_t ws_size,
                              hipStream_t stream) {
  const float* seq   = (const float*)d_in[0];
  const float* att   = (const float*)d_in[1];
  const float* headW = (const float*)d_in[2];
  const float* headb = (const float*)d_in[3];
  const float* tailW = (const float*)d_in[4];
  const float* tailb = (const float*)d_in[5];
  const float* projW = (const float*)d_in[6];
  const float* clsW  = (const float*)d_in[7];
  const float* clsb  = (const float*)d_in[8];
  const float* mmask = (const float*)d_in[9];
  const int* midx = (const int*)d_in[10];
  const int* hts  = (const int*)d_in[11];

  char* p = (char*)d_ws;
  auto alloc_f = [&](size_t n){ float* r = (float*)p; p += n*sizeof(float); return r; };
  auto alloc_b = [&](size_t n){ __bf16* r = (__bf16*)p; p += n*2; return r; };
  float* hpre    = alloc_f((size_t)B_*NE_*EMB_);
  float* tpre    = alloc_f((size_t)B_*NE_*EMB_);
  __bf16* e_embB = alloc_b((size_t)128*H_);
  __bf16* e_att  = alloc_b((size_t)B_*NE_*NH_*L_);
  __bf16* htattb = alloc_b((size_t)2464*L_);
  __bf16* seqT   = alloc_b((size_t)B_*H_*L_);
  __bf16* rsb    = alloc_b((size_t)2432*H_);
  __bf16* Wt     = alloc_b((size_t)2*H_*2*H_);
  __bf16* clsA   = alloc_b((size_t)128*H_);
  __bf16* WcT    = alloc_b((size_t)128*EMB_*BS_);
  __bf16* projWT = alloc_b((size_t)EMB_*BS_*H_);
  // hs/ts alias projWT (projWT dead after k_mid's wc branch)
  __bf16* hsb = projWT;
  __bf16* tsb = projWT + (size_t)B_*P_*EMB_;

  // zero output for the K-split atomic combine in k_logits
  hipMemsetAsync(d_out, 0, (size_t)B_*P_*NC_*sizeof(float), stream);

  k_prep<<<S1_CVT + S1_TPW + S1_TPS + S1_POOL + S1_ATT, 256, 0, stream>>>(
      seq, att, headW, tailW, projW, clsW, mmask, midx,
      Wt, clsA, projWT, seqT, e_embB, e_att);
  k_mid<<<S2_WC + S2_PRE + S2_HT, 256, 0, stream>>>(
      clsA, projWT, e_att, hts, e_embB, Wt, WcT, htattb, hpre, tpre);
  k_rs_mfma<<<dim3(H_/64, 10, B_), 256, 0, stream>>>(htattb, seqT, rsb);
  k_extract_mfma<<<dim3(EMB_/64, 38, 2), 256, 0, stream>>>(
      rsb, Wt, headb, tailb, hpre, tpre, hts, hsb, tsb);
  k_logits_mfma<<<600, 512, 0, stream>>>(hsb, tsb, WcT, clsb, (float*)d_out);
}